// Round 3
// baseline (203.284 us; speedup 1.0000x reference)
//
#include <hip/hip_runtime.h>
#include <math.h>

// YOLO loss — branchless single-path version.
// Each wave owns 64 consecutive cells. pred staged to LDS via 8 unconditional
// coalesced float4 loads (indices clamped, never branched). Class loss sweeps
// the wave's contiguous tcls span with all 5 loads batched (no divergent
// guards -> compiler issues them together); mask applied as float multiplier.
// Box/IoU math fully branchless (select via multipliers).
// Blocks write float4 partials {cls,noobj,reg,cont} to ws; k_final reduces.

#define BLOCK 256
#define WPB 4            // waves per block
#define CPW 64           // cells per wave

__global__ __launch_bounds__(BLOCK) void k_yolo(
    const float*  __restrict__ pred,
    const float4* __restrict__ tbox4,
    const float4* __restrict__ tcls4,
    const int*    __restrict__ mask,
    float4*       __restrict__ partial,
    int n_cells)
{
    __shared__ float  sp[WPB][CPW * 30];   // 30720 B
    __shared__ float4 swr[WPB];
    const int tid  = threadIdx.x;
    const int lane = tid & 63;
    const int w    = tid >> 6;
    const long long cell0 = ((long long)blockIdx.x * WPB + w) * CPW;
    // Safe base: if this wave's tile starts past the end (can't happen with
    // grid sized from n_cells unless n_cells%256!=0), slide back; all lanes
    // then have vf=0 and contribute nothing.
    const long long base = (cell0 < (long long)n_cells) ? cell0
                         : (long long)n_cells - CPW;
    const int remc = (int)(((long long)n_cells - base) < CPW
                           ? ((long long)n_cells - base) : CPW);   // 1..64
    const int lim4 = (remc * 30) >> 2;      // valid float4s of pred tile (<=480)
    const int lim5 = remc * 5;              // valid float4s of tcls tile (<=320)

    const bool  vf  = (cell0 + (long long)lane) < (long long)n_cells;
    const float vff = vf ? 1.0f : 0.0f;
    const int   li  = (lane < remc) ? lane : (remc - 1);  // clamped lane->cell

    // ---- issue all global loads for this tile (branchless, clamped) ----
    const float4* p4 = reinterpret_cast<const float4*>(pred + base * 30);
    float4* s4 = reinterpret_cast<float4*>(sp[w]);
    int   mraw = mask[base + li];
    float4 tb  = tbox4[base + li];
    #pragma unroll
    for (int i = 0; i < 8; ++i) {
        int k = lane + i * 64;
        k = (k < lim4) ? k : (lim4 - 1);    // clamp: dup loads/writes are benign
        s4[k] = p4[k];
    }
    const int   mflag = vf ? mraw : 0;
    const float mff   = (float)mflag;

    __syncthreads();   // staged LDS visible to all lanes of the block

    // ---- per-lane box terms (branchless) ----
    float cls = 0.f, noobj, reg, cont;
    {
        const float2* pc2 = reinterpret_cast<const float2*>(sp[w] + lane * 30);
        float2 v0 = pc2[0], v1 = pc2[1], v2 = pc2[2], v3 = pc2[3], v4 = pc2[4];
        // box0 = (v0.x,v0.y,v1.x,v1.y | conf v2.x); box1 = (v2.y,v3.x,v3.y,v4.x | conf v4.y)
        float txc = tb.x / 14.0f, tyc = tb.y / 14.0f;
        float t0 = txc - 0.5f * tb.z, t1 = tyc - 0.5f * tb.w;
        float t2 = txc + 0.5f * tb.z, t3 = tyc + 0.5f * tb.w;
        float area_t = (t2 - t0) * (t3 - t1);
        float bx[2] = { v0.x, v2.y }, by[2] = { v0.y, v3.x };
        float bw[2] = { v1.x, v3.y }, bh[2] = { v1.y, v4.x };
        float bcf[2] = { v2.x, v4.y };
        float iou[2];
        #pragma unroll
        for (int b = 0; b < 2; ++b) {
            float px = bx[b] / 14.0f, py = by[b] / 14.0f;
            float q0 = px - 0.5f * bw[b], q1 = py - 0.5f * bh[b];
            float q2 = px + 0.5f * bw[b], q3 = py + 0.5f * bh[b];
            float lt0 = fmaxf(t0, q0), lt1 = fmaxf(t1, q1);
            float rb0 = fminf(t2, q2), rb1 = fminf(t3, q3);
            float ww = fmaxf(rb0 - lt0, 0.f), hh = fmaxf(rb1 - lt1, 0.f);
            float inter = ww * hh;
            float area_p = (q2 - q0) * (q3 - q1);
            iou[b] = inter / (area_t + area_p - inter);
        }
        int bi = (iou[1] > iou[0]) ? 1 : 0;       // jnp.argmax first-max rule
        float dx = bx[bi] - tb.x, dy = by[bi] - tb.y;
        float swd = sqrtf(bw[bi]) - sqrtf(tb.z);  // inputs > 0, no NaN risk
        float shd = sqrtf(bh[bi]) - sqrtf(tb.w);
        reg  = mff * 5.0f * (dx*dx + dy*dy + swd*swd + shd*shd);
        float dco = iou[bi] - bcf[bi];
        cont = mff * dco * dco;
        noobj = (vff - mff) * 0.5f * (v2.x * v2.x + v4.y * v4.y);
    }

    // ---- class loss: sweep wave's contiguous tcls span, loads batched ----
    {
        const float4* t4 = tcls4 + base * 5;
        float4 t[5];
        float2 a[5], b2[5];
        float  mc[5];
        #pragma unroll
        for (int i = 0; i < 5; ++i) {
            int j = lane + i * 64;                 // 0..319
            int jc = (j < lim5) ? j : (lim5 - 1);  // clamp (tail only)
            t[i] = t4[jc];                         // unconditional -> batched
            int c = j / 5;                         // local cell 0..63 (magic mul)
            int q = j - 5 * c;                     // float4 idx in cell 0..4
            int m = __shfl(mflag, c, 64);
            mc[i] = (j < lim5) ? (float)m : 0.0f;
            const float2* s2 = reinterpret_cast<const float2*>(sp[w] + c * 30 + 10 + q * 4);
            a[i]  = s2[0];
            b2[i] = s2[1];
        }
        #pragma unroll
        for (int i = 0; i < 5; ++i) {
            float d0 = t[i].x - a[i].x,  d1 = t[i].y - a[i].y;
            float d2 = t[i].z - b2[i].x, d3 = t[i].w - b2[i].y;
            cls += mc[i] * (d0*d0 + d1*d1 + d2*d2 + d3*d3);
        }
    }

    // ---- wave shuffle reduce, block reduce, store partial ----
    #pragma unroll
    for (int off = 32; off; off >>= 1) {
        cls   += __shfl_down(cls,   off, 64);
        noobj += __shfl_down(noobj, off, 64);
        reg   += __shfl_down(reg,   off, 64);
        cont  += __shfl_down(cont,  off, 64);
    }
    if (lane == 0) swr[w] = make_float4(cls, noobj, reg, cont);
    __syncthreads();
    if (tid == 0) {
        float4 a = swr[0];
        #pragma unroll
        for (int i = 1; i < WPB; ++i) {
            float4 b = swr[i];
            a.x += b.x; a.y += b.y; a.z += b.z; a.w += b.w;
        }
        partial[blockIdx.x] = a;
    }
}

__global__ __launch_bounds__(BLOCK) void k_final(
    const float4* __restrict__ partial, int nblocks,
    float* __restrict__ out, float invN)
{
    float4 acc = make_float4(0.f, 0.f, 0.f, 0.f);
    for (int b = threadIdx.x; b < nblocks; b += BLOCK) {
        float4 v = partial[b];
        acc.x += v.x; acc.y += v.y; acc.z += v.z; acc.w += v.w;
    }
    #pragma unroll
    for (int off = 32; off; off >>= 1) {
        acc.x += __shfl_down(acc.x, off, 64);
        acc.y += __shfl_down(acc.y, off, 64);
        acc.z += __shfl_down(acc.z, off, 64);
        acc.w += __shfl_down(acc.w, off, 64);
    }
    __shared__ float4 sw[WPB];
    int lane = threadIdx.x & 63, w = threadIdx.x >> 6;
    if (lane == 0) sw[w] = acc;
    __syncthreads();
    if (threadIdx.x == 0) {
        float cls = 0.f, noobj = 0.f, reg = 0.f, cont = 0.f;
        #pragma unroll
        for (int i = 0; i < WPB; ++i) {
            cls += sw[i].x; noobj += sw[i].y; reg += sw[i].z; cont += sw[i].w;
        }
        out[0] = (cls + noobj + reg + cont) * invN;
        out[1] = reg;
        out[2] = cont;
        out[3] = noobj;
        out[4] = cls;
    }
}

extern "C" void kernel_launch(void* const* d_in, const int* in_sizes, int n_in,
                              void* d_out, int out_size, void* d_ws, size_t ws_size,
                              hipStream_t stream) {
    const float*  pred  = (const float*)d_in[0];   // (N,14,14,30) f32
    const float4* tbox4 = (const float4*)d_in[1];  // (N,14,14,4)  f32
    const float4* tcls4 = (const float4*)d_in[2];  // (N,14,14,20) f32
    const int*    mask  = (const int*)d_in[3];     // (N,14,14)    int32 (verified R1)
    float* out = (float*)d_out;
    float4* partial = (float4*)d_ws;

    int n_cells = in_sizes[3];
    int N = in_sizes[0] / (14 * 14 * 30);
    int nblocks = (n_cells + BLOCK - 1) / BLOCK;

    hipLaunchKernelGGL(k_yolo, dim3(nblocks), dim3(BLOCK), 0, stream,
                       pred, tbox4, tcls4, mask, partial, n_cells);
    hipLaunchKernelGGL(k_final, dim3(1), dim3(BLOCK), 0, stream,
                       partial, nblocks, out, 1.0f / (float)N);
}

// Round 4
// 203.264 us; speedup vs baseline: 1.0001x; 1.0001x over previous
//
#include <hip/hip_runtime.h>
#include <math.h>

// YOLO loss — MLP-maximized version.
// Each wave owns 64 consecutive cells, staged into a PRIVATE LDS region via
// global_load_lds width-16 (no VGPR round-trip -> all 8 issues in flight).
// tbox/mask/tcls VGPR loads issued before a single vmcnt(0) wait: one memory
// latency exposure per wave, no staging barrier (waves fully independent).
// Mask distributed via 64-bit ballot. Block partials -> k_final reduce.

#define BLOCK 256
#define WPB 4            // waves per block
#define CPW 64           // cells per wave

typedef __attribute__((address_space(3))) void       lds_void_t;
typedef __attribute__((address_space(1))) const void gbl_void_t;

__global__ __launch_bounds__(BLOCK, 4) void k_yolo(
    const float*  __restrict__ pred,
    const float4* __restrict__ tbox4,
    const float4* __restrict__ tcls4,
    const int*    __restrict__ mask,
    float4*       __restrict__ partial,
    int n_cells)
{
    __shared__ float  sp[WPB][CPW * 30];   // 7680 B per wave, 30720 B/block
    __shared__ float4 swr[WPB];
    const int tid  = threadIdx.x;
    const int lane = tid & 63;
    const int w    = tid >> 6;
    const long long nc    = n_cells;
    const long long cell0 = ((long long)blockIdx.x * WPB + w) * CPW;
    const long long base  = (cell0 < nc) ? cell0 : (nc - CPW);   // tail-safe
    const int remc = (int)(((nc - base) < CPW) ? (nc - base) : CPW);
    const int lim5 = remc * 5;                   // valid tcls float4s (<=320)
    const int li   = (lane < remc) ? lane : (remc - 1);

    // ---- stage pred tile: 7680 B via global_load_lds (7 full + 1 half) ----
    const char* gb   = (const char*)pred + base * 120;
    const char* gend = (const char*)pred + nc * 120 - 16;   // clamp target
    char* lb = (char*)&sp[w][0];
    #pragma unroll
    for (int i = 0; i < 7; ++i) {
        const char* ga = gb + i * 1024 + lane * 16;
        if (ga > gend) ga = gend;               // safety clamp (dup -> pad-free)
        __builtin_amdgcn_global_load_lds((gbl_void_t*)ga,
                                         (lds_void_t*)(lb + i * 1024), 16, 0, 0);
    }
    if (lane < 32) {                            // last 512 B of the tile
        const char* ga = gb + 7168 + lane * 16;
        if (ga > gend) ga = gend;
        __builtin_amdgcn_global_load_lds((gbl_void_t*)ga,
                                         (lds_void_t*)(lb + 7168), 16, 0, 0);
    }

    // ---- issue all VGPR loads before the single wait ----
    int    mraw = mask[base + li];
    float4 tb   = tbox4[base + li];
    const float4* t4 = tcls4 + base * 5;
    float4 t[5];
    #pragma unroll
    for (int i = 0; i < 5; ++i) {
        int j  = lane + i * 64;                 // 0..319
        int jc = (j < lim5) ? j : (lim5 - 1);
        t[i] = t4[jc];
    }

    // ---- one drain for everything; fence LDS reads behind it ----
    __builtin_amdgcn_s_waitcnt(0xF70);          // vmcnt(0), lgkm/exp unconstrained
    __asm__ volatile("" ::: "memory");

    const bool  vf    = (cell0 + (long long)lane) < nc;
    const int   mflag = vf ? mraw : 0;
    const float mff   = (float)mflag;
    const float vff   = vf ? 1.0f : 0.0f;
    const unsigned long long mbits = __ballot(mflag != 0);

    // ---- per-lane box terms (wave-private LDS reads) ----
    float cls = 0.f, noobj, reg, cont;
    {
        const float2* pc2 = reinterpret_cast<const float2*>(sp[w] + lane * 30);
        float2 v0 = pc2[0], v1 = pc2[1], v2 = pc2[2], v3 = pc2[3], v4 = pc2[4];
        // box0 = (v0.x,v0.y,v1.x,v1.y | conf v2.x); box1 = (v2.y,v3.x,v3.y,v4.x | conf v4.y)
        float txc = tb.x / 14.0f, tyc = tb.y / 14.0f;
        float t0 = txc - 0.5f * tb.z, t1 = tyc - 0.5f * tb.w;
        float t2 = txc + 0.5f * tb.z, t3 = tyc + 0.5f * tb.w;
        float area_t = (t2 - t0) * (t3 - t1);
        float bx[2] = { v0.x, v2.y }, by[2] = { v0.y, v3.x };
        float bw[2] = { v1.x, v3.y }, bh[2] = { v1.y, v4.x };
        float bcf[2] = { v2.x, v4.y };
        float iou[2];
        #pragma unroll
        for (int b = 0; b < 2; ++b) {
            float px = bx[b] / 14.0f, py = by[b] / 14.0f;
            float q0 = px - 0.5f * bw[b], q1 = py - 0.5f * bh[b];
            float q2 = px + 0.5f * bw[b], q3 = py + 0.5f * bh[b];
            float lt0 = fmaxf(t0, q0), lt1 = fmaxf(t1, q1);
            float rb0 = fminf(t2, q2), rb1 = fminf(t3, q3);
            float ww = fmaxf(rb0 - lt0, 0.f), hh = fmaxf(rb1 - lt1, 0.f);
            float inter = ww * hh;
            float area_p = (q2 - q0) * (q3 - q1);
            iou[b] = inter / (area_t + area_p - inter);
        }
        int bi = (iou[1] > iou[0]) ? 1 : 0;       // jnp.argmax first-max rule
        float dx = bx[bi] - tb.x, dy = by[bi] - tb.y;
        float swd = sqrtf(bw[bi]) - sqrtf(tb.z);  // inputs > 0
        float shd = sqrtf(bh[bi]) - sqrtf(tb.w);
        reg  = mff * 5.0f * (dx*dx + dy*dy + swd*swd + shd*shd);
        float dco = iou[bi] - bcf[bi];
        cont = mff * dco * dco;
        noobj = (vff - mff) * 0.5f * (v2.x * v2.x + v4.y * v4.y);
    }

    // ---- class loss: wave sweeps its contiguous tcls span ----
    #pragma unroll
    for (int i = 0; i < 5; ++i) {
        int j = lane + i * 64;                    // 0..319
        int c = j / 5;                            // local cell 0..63
        int q = j - 5 * c;                        // float4 idx in cell 0..4
        float mcf = (float)((int)((mbits >> c) & 1ull));
        mcf = (j < lim5) ? mcf : 0.0f;
        const float2* s2 = reinterpret_cast<const float2*>(sp[w] + c * 30 + 10 + q * 4);
        float2 a = s2[0], b2 = s2[1];
        float d0 = t[i].x - a.x,  d1 = t[i].y - a.y;
        float d2 = t[i].z - b2.x, d3 = t[i].w - b2.y;
        cls += mcf * (d0*d0 + d1*d1 + d2*d2 + d3*d3);
    }

    // ---- wave shuffle reduce, block reduce, store partial ----
    #pragma unroll
    for (int off = 32; off; off >>= 1) {
        cls   += __shfl_down(cls,   off, 64);
        noobj += __shfl_down(noobj, off, 64);
        reg   += __shfl_down(reg,   off, 64);
        cont  += __shfl_down(cont,  off, 64);
    }
    if (lane == 0) swr[w] = make_float4(cls, noobj, reg, cont);
    __syncthreads();
    if (tid == 0) {
        float4 a = swr[0];
        #pragma unroll
        for (int i = 1; i < WPB; ++i) {
            float4 b = swr[i];
            a.x += b.x; a.y += b.y; a.z += b.z; a.w += b.w;
        }
        partial[blockIdx.x] = a;
    }
}

__global__ __launch_bounds__(BLOCK) void k_final(
    const float4* __restrict__ partial, int nblocks,
    float* __restrict__ out, float invN)
{
    float4 acc = make_float4(0.f, 0.f, 0.f, 0.f);
    for (int b = threadIdx.x; b < nblocks; b += BLOCK) {
        float4 v = partial[b];
        acc.x += v.x; acc.y += v.y; acc.z += v.z; acc.w += v.w;
    }
    #pragma unroll
    for (int off = 32; off; off >>= 1) {
        acc.x += __shfl_down(acc.x, off, 64);
        acc.y += __shfl_down(acc.y, off, 64);
        acc.z += __shfl_down(acc.z, off, 64);
        acc.w += __shfl_down(acc.w, off, 64);
    }
    __shared__ float4 sw[WPB];
    int lane = threadIdx.x & 63, w = threadIdx.x >> 6;
    if (lane == 0) sw[w] = acc;
    __syncthreads();
    if (threadIdx.x == 0) {
        float cls = 0.f, noobj = 0.f, reg = 0.f, cont = 0.f;
        #pragma unroll
        for (int i = 0; i < WPB; ++i) {
            cls += sw[i].x; noobj += sw[i].y; reg += sw[i].z; cont += sw[i].w;
        }
        out[0] = (cls + noobj + reg + cont) * invN;
        out[1] = reg;
        out[2] = cont;
        out[3] = noobj;
        out[4] = cls;
    }
}

extern "C" void kernel_launch(void* const* d_in, const int* in_sizes, int n_in,
                              void* d_out, int out_size, void* d_ws, size_t ws_size,
                              hipStream_t stream) {
    const float*  pred  = (const float*)d_in[0];   // (N,14,14,30) f32
    const float4* tbox4 = (const float4*)d_in[1];  // (N,14,14,4)  f32
    const float4* tcls4 = (const float4*)d_in[2];  // (N,14,14,20) f32
    const int*    mask  = (const int*)d_in[3];     // (N,14,14)    int32 (verified R1)
    float* out = (float*)d_out;
    float4* partial = (float4*)d_ws;

    int n_cells = in_sizes[3];
    int N = in_sizes[0] / (14 * 14 * 30);
    int nblocks = (n_cells + BLOCK - 1) / BLOCK;

    hipLaunchKernelGGL(k_yolo, dim3(nblocks), dim3(BLOCK), 0, stream,
                       pred, tbox4, tcls4, mask, partial, n_cells);
    hipLaunchKernelGGL(k_final, dim3(1), dim3(BLOCK), 0, stream,
                       partial, nblocks, out, 1.0f / (float)N);
}

// Round 6
// 202.136 us; speedup vs baseline: 1.0057x; 1.0056x over previous
//
#include <hip/hip_runtime.h>
#include <math.h>

// YOLO loss — fat-block looped version.
// 784 blocks (fully co-resident) instead of 3136: tests the dispatch-rate
// hypothesis. Each wave processes TPW=4 consecutive 64-cell tiles. Loop body:
//   vmcnt(0) [tile s landed] -> ds_read tile s into regs -> lgkmcnt(0)
//   -> issue tile s+1 (DMA into same LDS buf + VGPR loads into alt ctx)
//   -> compute tile s  (tile s+1 latency hides under it)
// All waits are conservative (vmcnt(0)/lgkmcnt(0)) — no counting fragility.
// R5's bug (missing vmcnt wait before first LDS read) is fixed.

#define BLOCK 256
#define WPB 4            // waves per block
#define CPW 64           // cells per tile
#define TPW 4            // tiles per wave

typedef __attribute__((address_space(3))) void       lds_void_t;
typedef __attribute__((address_space(1))) const void gbl_void_t;
typedef float vf4 __attribute__((ext_vector_type(4)));

struct TileCtx {
    long long cell0;     // unclamped first cell (validity test)
    int       lim5;      // valid tcls float4s in tile
    int       mraw;
    vf4       tb;
    vf4       t[5];
};

__device__ __forceinline__ void issue_tile(
    long long tile, long long ntiles, long long nc, int lane,
    const float* __restrict__ pred, const vf4* __restrict__ tbox4,
    const vf4* __restrict__ tcls4, const int* __restrict__ mask,
    char* lb, TileCtx& cx)
{
    cx.cell0 = tile * CPW;
    long long tt = (tile < ntiles) ? tile : (ntiles - 1);
    long long b  = tt * CPW;
    b = (b + CPW <= nc) ? b : (nc - CPW);
    int remc = (int)(((nc - b) < (long long)CPW) ? (nc - b) : CPW);
    cx.lim5 = remc * 5;
    int li = (lane < remc) ? lane : (remc - 1);

    // pred tile: 7680 B via global_load_lds width-16 (7 full + 1 half issue).
    // LDS dest is wave-uniform base + lane*16 (contract verified R4).
    const char* gb   = (const char*)pred + b * 120;
    const char* gend = (const char*)pred + nc * 120 - 16;
    #pragma unroll
    for (int i = 0; i < 7; ++i) {
        const char* ga = gb + i * 1024 + (long long)lane * 16;
        if (ga > gend) ga = gend;
        __builtin_amdgcn_global_load_lds((gbl_void_t*)ga,
                                         (lds_void_t*)(lb + i * 1024), 16, 0, 0);
    }
    if (lane < 32) {
        const char* ga = gb + 7168 + (long long)lane * 16;
        if (ga > gend) ga = gend;
        __builtin_amdgcn_global_load_lds((gbl_void_t*)ga,
                                         (lds_void_t*)(lb + 7168), 16, 0, 0);
    }
    cx.mraw = mask[b + li];
    cx.tb   = tbox4[b + li];
    const vf4* t4 = tcls4 + b * 5;
    #pragma unroll
    for (int i = 0; i < 5; ++i) {
        int j  = lane + i * 64;
        int jc = (j < cx.lim5) ? j : (cx.lim5 - 1);
        cx.t[i] = __builtin_nontemporal_load(&t4[jc]);   // single-touch data
    }
}

// Pull this lane's needs from the staged tile into registers
// (compute phase then touches no LDS).
__device__ __forceinline__ void read_pred(
    const float* spw, int lane,
    float2 (&v)[5], float2 (&pa)[5], float2 (&pb)[5])
{
    const float2* pc2 = reinterpret_cast<const float2*>(spw + lane * 30);
    #pragma unroll
    for (int i = 0; i < 5; ++i) v[i] = pc2[i];
    #pragma unroll
    for (int i = 0; i < 5; ++i) {
        int j = lane + i * 64;                 // 0..319
        int c = j / 5;                         // local cell
        int q = j - 5 * c;                     // float4 idx in cls block
        const float2* s2 = reinterpret_cast<const float2*>(spw + c * 30 + 10 + q * 4);
        pa[i] = s2[0];
        pb[i] = s2[1];
    }
}

__device__ __forceinline__ void compute_tile(
    int lane, long long nc, const TileCtx& cx,
    const float2 (&v)[5], const float2 (&pa)[5], const float2 (&pb)[5],
    float& cls, float& noobj, float& reg, float& cont)
{
    const bool  vfb   = (cx.cell0 + (long long)lane) < nc;
    const int   mflag = vfb ? cx.mraw : 0;
    const float mff   = (float)mflag;
    const float vff   = vfb ? 1.0f : 0.0f;
    const unsigned long long mbits = __ballot(mflag != 0);

    {   // box terms
        vf4 tb = cx.tb;
        float txc = tb.x / 14.0f, tyc = tb.y / 14.0f;
        float t0 = txc - 0.5f * tb.z, t1 = tyc - 0.5f * tb.w;
        float t2 = txc + 0.5f * tb.z, t3 = tyc + 0.5f * tb.w;
        float area_t = (t2 - t0) * (t3 - t1);
        // box0 = (v0.x,v0.y,v1.x,v1.y | conf v2.x); box1 = (v2.y,v3.x,v3.y,v4.x | conf v4.y)
        float bx[2] = { v[0].x, v[2].y }, by[2] = { v[0].y, v[3].x };
        float bw[2] = { v[1].x, v[3].y }, bh[2] = { v[1].y, v[4].x };
        float bcf[2] = { v[2].x, v[4].y };
        float iou[2];
        #pragma unroll
        for (int b = 0; b < 2; ++b) {
            float px = bx[b] / 14.0f, py = by[b] / 14.0f;
            float q0 = px - 0.5f * bw[b], q1 = py - 0.5f * bh[b];
            float q2 = px + 0.5f * bw[b], q3 = py + 0.5f * bh[b];
            float lt0 = fmaxf(t0, q0), lt1 = fmaxf(t1, q1);
            float rb0 = fminf(t2, q2), rb1 = fminf(t3, q3);
            float ww = fmaxf(rb0 - lt0, 0.f), hh = fmaxf(rb1 - lt1, 0.f);
            float inter = ww * hh;
            float area_p = (q2 - q0) * (q3 - q1);
            iou[b] = inter / (area_t + area_p - inter);
        }
        int bi = (iou[1] > iou[0]) ? 1 : 0;       // jnp.argmax first-max rule
        float dx = bx[bi] - tb.x, dy = by[bi] - tb.y;
        float swd = sqrtf(bw[bi]) - sqrtf(tb.z);  // inputs > 0
        float shd = sqrtf(bh[bi]) - sqrtf(tb.w);
        reg  += mff * 5.0f * (dx*dx + dy*dy + swd*swd + shd*shd);
        float dco = iou[bi] - bcf[bi];
        cont += mff * dco * dco;
        noobj += (vff - mff) * 0.5f * (v[2].x * v[2].x + v[4].y * v[4].y);
    }
    // class terms
    #pragma unroll
    for (int i = 0; i < 5; ++i) {
        int j = lane + i * 64;
        int c = j / 5;
        float mcf = (float)((int)((mbits >> c) & 1ull));
        if (j >= cx.lim5) mcf = 0.0f;
        float d0 = cx.t[i].x - pa[i].x,  d1 = cx.t[i].y - pa[i].y;
        float d2 = cx.t[i].z - pb[i].x,  d3 = cx.t[i].w - pb[i].y;
        cls += mcf * (d0*d0 + d1*d1 + d2*d2 + d3*d3);
    }
}

__global__ __launch_bounds__(BLOCK) void k_yolo(
    const float* __restrict__ pred,
    const vf4*   __restrict__ tbox4,
    const vf4*   __restrict__ tcls4,
    const int*   __restrict__ mask,
    float4*      __restrict__ partial,
    int n_cells)
{
    __shared__ float  sp[WPB][CPW * 30];    // 7680 B per wave
    __shared__ float4 swr[WPB];
    const int tid  = threadIdx.x;
    const int lane = tid & 63;
    const int w    = tid >> 6;
    const long long nc     = n_cells;
    const long long ntiles = (nc + CPW - 1) / CPW;
    const long long g      = (long long)blockIdx.x * WPB + w;
    const long long tile0  = g * TPW;       // wave owns tiles tile0..tile0+3

    char*        lb  = (char*)&sp[w][0];
    const float* spw = &sp[w][0];

    float cls = 0.f, noobj = 0.f, reg = 0.f, cont = 0.f;
    float2 v[5], pa[5], pb[5];
    TileCtx cx[2];

    issue_tile(tile0, ntiles, nc, lane, pred, tbox4, tcls4, mask, lb, cx[0]);
    #pragma unroll
    for (int s = 0; s < TPW; ++s) {
        // tile s landed (DMA + VGPR loads are all vmcnt-tracked)
        __builtin_amdgcn_s_waitcnt(0x0F70);          // vmcnt(0)
        __asm__ volatile("" ::: "memory");
        read_pred(spw, lane, v, pa, pb);             // LDS -> regs
        __builtin_amdgcn_s_waitcnt(0xC07F);          // lgkmcnt(0): reads done (WAR vs next DMA)
        __asm__ volatile("" ::: "memory");
        __builtin_amdgcn_sched_barrier(0);
        if (s + 1 < TPW)                             // issue next tile now...
            issue_tile(tile0 + s + 1, ntiles, nc, lane,
                       pred, tbox4, tcls4, mask, lb, cx[(s + 1) & 1]);
        __builtin_amdgcn_sched_barrier(0);
        compute_tile(lane, nc, cx[s & 1], v, pa, pb, // ...and hide it here
                     cls, noobj, reg, cont);
    }

    // ---- wave shuffle reduce, block reduce, store partial ----
    #pragma unroll
    for (int off = 32; off; off >>= 1) {
        cls   += __shfl_down(cls,   off, 64);
        noobj += __shfl_down(noobj, off, 64);
        reg   += __shfl_down(reg,   off, 64);
        cont  += __shfl_down(cont,  off, 64);
    }
    if (lane == 0) swr[w] = make_float4(cls, noobj, reg, cont);
    __syncthreads();
    if (tid == 0) {
        float4 a = swr[0];
        #pragma unroll
        for (int i = 1; i < WPB; ++i) {
            float4 b = swr[i];
            a.x += b.x; a.y += b.y; a.z += b.z; a.w += b.w;
        }
        partial[blockIdx.x] = a;
    }
}

__global__ __launch_bounds__(256) void k_final(
    const float4* __restrict__ partial, int nblocks,
    float* __restrict__ out, float invN)
{
    float4 acc = make_float4(0.f, 0.f, 0.f, 0.f);
    for (int b = threadIdx.x; b < nblocks; b += 256) {
        float4 p = partial[b];
        acc.x += p.x; acc.y += p.y; acc.z += p.z; acc.w += p.w;
    }
    #pragma unroll
    for (int off = 32; off; off >>= 1) {
        acc.x += __shfl_down(acc.x, off, 64);
        acc.y += __shfl_down(acc.y, off, 64);
        acc.z += __shfl_down(acc.z, off, 64);
        acc.w += __shfl_down(acc.w, off, 64);
    }
    __shared__ float4 sw[4];
    int lane = threadIdx.x & 63, w = threadIdx.x >> 6;
    if (lane == 0) sw[w] = acc;
    __syncthreads();
    if (threadIdx.x == 0) {
        float cls = 0.f, noobj = 0.f, reg = 0.f, cont = 0.f;
        #pragma unroll
        for (int i = 0; i < 4; ++i) {
            cls += sw[i].x; noobj += sw[i].y; reg += sw[i].z; cont += sw[i].w;
        }
        out[0] = (cls + noobj + reg + cont) * invN;
        out[1] = reg;
        out[2] = cont;
        out[3] = noobj;
        out[4] = cls;
    }
}

extern "C" void kernel_launch(void* const* d_in, const int* in_sizes, int n_in,
                              void* d_out, int out_size, void* d_ws, size_t ws_size,
                              hipStream_t stream) {
    const float* pred  = (const float*)d_in[0];   // (N,14,14,30) f32
    const vf4*   tbox4 = (const vf4*)d_in[1];     // (N,14,14,4)  f32
    const vf4*   tcls4 = (const vf4*)d_in[2];     // (N,14,14,20) f32
    const int*   mask  = (const int*)d_in[3];     // (N,14,14)    int32 (verified R1)
    float* out = (float*)d_out;
    float4* partial = (float4*)d_ws;

    int n_cells = in_sizes[3];
    int N = in_sizes[0] / (14 * 14 * 30);
    long long ntiles  = (n_cells + CPW - 1) / CPW;          // 12544
    long long nwaves  = (ntiles + TPW - 1) / TPW;           // 3136
    int nblocks = (int)((nwaves + WPB - 1) / WPB);          // 784

    hipLaunchKernelGGL(k_yolo, dim3(nblocks), dim3(BLOCK), 0, stream,
                       pred, tbox4, tcls4, mask, partial, n_cells);
    hipLaunchKernelGGL(k_final, dim3(1), dim3(256), 0, stream,
                       partial, nblocks, out, 1.0f / (float)N);
}